// Round 4
// baseline (515.318 us; speedup 1.0000x reference)
//
#include <hip/hip_runtime.h>
#include <hip/hip_bf16.h>

#define TOK 16384   // B*S
#define E 2048
#define DH 128

using bf16x8 = __attribute__((ext_vector_type(8))) __bf16;
using f32x4  = __attribute__((ext_vector_type(4))) float;
using f32x16 = __attribute__((ext_vector_type(16))) float;
using u16x8  = __attribute__((ext_vector_type(8))) unsigned short;

static __device__ __forceinline__ unsigned short f2bf(float f) {
  union { float f; unsigned u; } x; x.f = f;
  unsigned r = x.u + 0x7fffu + ((x.u >> 16) & 1u);   // RNE
  return (unsigned short)(r >> 16);
}

static __device__ __forceinline__ void gload_lds16(const unsigned short* g, unsigned short* l) {
  __builtin_amdgcn_global_load_lds(
      (const __attribute__((address_space(1))) void*)g,
      (__attribute__((address_space(3))) void*)l, 16, 0, 0);
}

// ---------------- prep kernels ----------------
__global__ __launch_bounds__(256) void cvt_plain(const float* __restrict__ in,
                                                 unsigned short* __restrict__ out, int n8) {
  int stride = gridDim.x * blockDim.x;
  for (int i = blockIdx.x * blockDim.x + threadIdx.x; i < n8; i += stride) {
    const float4* p = reinterpret_cast<const float4*>(in) + (size_t)i * 2;
    float4 v0 = p[0], v1 = p[1];
    u16x8 o;
    o[0] = f2bf(v0.x); o[1] = f2bf(v0.y); o[2] = f2bf(v0.z); o[3] = f2bf(v0.w);
    o[4] = f2bf(v1.x); o[5] = f2bf(v1.y); o[6] = f2bf(v1.z); o[7] = f2bf(v1.w);
    *(reinterpret_cast<u16x8*>(out) + i) = o;
  }
}

__global__ __launch_bounds__(256) void cvt_scaled(const float* __restrict__ in,
                                                  const float* __restrict__ phase,
                                                  unsigned short* __restrict__ out, int n8) {
  const float rs = 0.08838834764831845f;  // 1/sqrt(128)
  int stride = gridDim.x * blockDim.x;
  for (int i = blockIdx.x * blockDim.x + threadIdx.x; i < n8; i += stride) {
    int row = i >> 8;
    float sc = sinf(phase[row]) * rs;
    const float4* p = reinterpret_cast<const float4*>(in) + (size_t)i * 2;
    float4 v0 = p[0], v1 = p[1];
    u16x8 o;
    o[0] = f2bf(v0.x * sc); o[1] = f2bf(v0.y * sc); o[2] = f2bf(v0.z * sc); o[3] = f2bf(v0.w * sc);
    o[4] = f2bf(v1.x * sc); o[5] = f2bf(v1.y * sc); o[6] = f2bf(v1.z * sc); o[7] = f2bf(v1.w * sc);
    *(reinterpret_cast<u16x8*>(out) + i) = o;
  }
}

__global__ __launch_bounds__(256) void scale_bias(const float* __restrict__ bz,
                                                  const float* __restrict__ phase,
                                                  float* __restrict__ out) {
  const float rs = 0.08838834764831845f;
  int i = blockIdx.x * blockDim.x + threadIdx.x;
  if (i < E) out[i] = bz[i] * sinf(phase[i]) * rs;
}

// ---------------- 256x256 8-phase GEMM, 32x32x16 MFMA ----------------
#define MFMA16 __builtin_amdgcn_mfma_f32_16x16x32_bf16
#define MFMA32 __builtin_amdgcn_mfma_f32_32x32x16_bf16

// swizzled LDS fragment read: slot ^= row&7  (slot = 16B unit, 8 per 128B row)
static __device__ __forceinline__ bf16x8 ldf(const unsigned short* buf, int row, int slot) {
  return *reinterpret_cast<const bf16x8*>(buf + row * 64 + ((slot ^ (row & 7)) << 3));
}

// stage one 128-row half-tile: 2 x global_load_lds(16B) per thread.
static __device__ __forceinline__ void stage_half(const unsigned short* gbase, int K_,
                                                  unsigned short* dsthalf,
                                                  int r, int slot, int wave) {
#pragma unroll
  for (int c = 0; c < 2; ++c)
    gload_lds16(gbase + (size_t)(c * 64 + r) * K_ + slot * 8,
                dsthalf + c * 4096 + wave * 512);
}

// 8 MFMA: 2 M-tiles x 1 N-tile x 4 K-slices of 16
static __device__ __forceinline__ void quad32(f32x16 (&acc)[4][2], const bf16x8 (&a)[2][4],
                                              const bf16x8 (&b)[4], int mh, int nh) {
#pragma unroll
  for (int ks = 0; ks < 4; ++ks)
#pragma unroll
    for (int mi = 0; mi < 2; ++mi)
      acc[mh * 2 + mi][nh] = MFMA32(a[mi][ks], b[ks], acc[mh * 2 + mi][nh], 0, 0, 0);
}

#define PH_BAR()  __builtin_amdgcn_s_barrier()
#define PH_LGKM() asm volatile("s_waitcnt lgkmcnt(0)" ::: "memory")
#define PRIO1()   __builtin_amdgcn_s_setprio(1)
#define PRIO0()   __builtin_amdgcn_s_setprio(0)

// A fragments: 2 M-tiles (rows base, base+32) x 4 k-slices. 8 x ds_read_b128.
#define LD_A32(dst, buf, base)                                           \
  _Pragma("unroll")                                                      \
  for (int mi = 0; mi < 2; ++mi)                                         \
    _Pragma("unroll")                                                    \
    for (int ks = 0; ks < 4; ++ks)                                       \
      dst[mi][ks] = ldf(buf, (base) + mi * 32, ks * 2 + hi);

// B fragments: 1 N-tile x 4 k-slices. 4 x ds_read_b128.
#define LD_B32(dst, buf, base)                                           \
  _Pragma("unroll")                                                      \
  for (int ks = 0; ks < 4; ++ks)                                         \
    dst[ks] = ldf(buf, (base), ks * 2 + hi);

template <bool LAST>
static __device__ __forceinline__ void k_iter(
    const unsigned short* __restrict__ Ag, const unsigned short* __restrict__ Bg,
    int K_, int t,
    unsigned short* sA0, unsigned short* sA1, unsigned short* sB0, unsigned short* sB1,
    int r, int slot, int wave, int hi, int rA, int rB,
    bf16x8 (&bP)[4], bf16x8 (&bQ)[4], f32x16 (&acc)[4][2]) {
  const size_t k1 = (size_t)(t + 1) * 64, k2 = (size_t)(t + 2) * 64, k3 = (size_t)(t + 3) * 64;
  const size_t hB = (size_t)128 * K_;
  bf16x8 aF[2][4], b1F[4];

  // ---- ph1: read A.mh0 (8) ; stage t+1.A0
  LD_A32(aF, sA0, rA);
  stage_half(Ag + k1, K_, sA1, r, slot, wave);
  PH_BAR(); PH_LGKM();
  PRIO1(); quad32(acc, aF, bP, 0, 0); PRIO0();
  PH_BAR();

  // ---- ph2: read B.nh1 (4) ; stage t+1.A1
  LD_B32(b1F, sB0, rB + 32);
  stage_half(Ag + hB + k1, K_, sA1 + 8192, r, slot, wave);
  PH_BAR(); PH_LGKM();
  PRIO1(); quad32(acc, aF, b1F, 0, 1); PRIO0();
  PH_BAR();

  // ---- ph3: read A.mh1 (8) ; stage t+2.B0
  LD_A32(aF, sA0, rA + 64);
  if (!LAST) stage_half(Bg + k2, K_, sB0, r, slot, wave);
  PH_BAR(); PH_LGKM();
  PRIO1(); quad32(acc, aF, b1F, 1, 1); PRIO0();
  PH_BAR();

  // ---- ph4: stage t+2.B1 ; counted vmcnt (t+1 landed) ; MFMA ; prefetch bQ = B(t+1).nh0
  if (!LAST) {
    stage_half(Bg + hB + k2, K_, sB0 + 8192, r, slot, wave);
    asm volatile("s_waitcnt vmcnt(4)" ::: "memory");
  } else {
    asm volatile("s_waitcnt vmcnt(0)" ::: "memory");
  }
  PH_BAR();
  PRIO1(); quad32(acc, aF, bP, 1, 0); PRIO0();
  LD_B32(bQ, sB1, rB);
  PH_BAR();

  // ---- ph5: read A.mh0 (8) from buf1 ; stage t+2.A0
  LD_A32(aF, sA1, rA);
  if (!LAST) stage_half(Ag + k2, K_, sA0, r, slot, wave);
  PH_BAR(); PH_LGKM();
  PRIO1(); quad32(acc, aF, bQ, 0, 0); PRIO0();
  PH_BAR();

  // ---- ph6: read B.nh1 (4) ; stage t+2.A1
  LD_B32(b1F, sB1, rB + 32);
  if (!LAST) stage_half(Ag + hB + k2, K_, sA0 + 8192, r, slot, wave);
  PH_BAR(); PH_LGKM();
  PRIO1(); quad32(acc, aF, b1F, 0, 1); PRIO0();
  PH_BAR();

  // ---- ph7: read A.mh1 (8) ; stage t+3.B0
  LD_A32(aF, sA1, rA + 64);
  if (!LAST) stage_half(Bg + k3, K_, sB1, r, slot, wave);
  PH_BAR(); PH_LGKM();
  PRIO1(); quad32(acc, aF, b1F, 1, 1); PRIO0();
  PH_BAR();

  // ---- ph8: stage t+3.B1 ; counted vmcnt (t+2 landed) ; MFMA ; prefetch bP = B(t+2).nh0
  if (!LAST) {
    stage_half(Bg + hB + k3, K_, sB1 + 8192, r, slot, wave);
    asm volatile("s_waitcnt vmcnt(4)" ::: "memory");
  }
  PH_BAR();
  PRIO1(); quad32(acc, aF, bQ, 1, 0); PRIO0();
  if (!LAST) { LD_B32(bP, sB0, rB); }
  PH_BAR();
}

template <bool OUT_BF16>
__global__ __launch_bounds__(512, 2) void gemm256(const unsigned short* __restrict__ A,
                                                  const unsigned short* __restrict__ Bm,
                                                  const float* __restrict__ bias,
                                                  void* __restrict__ C,
                                                  int M, int N, int K_) {
  extern __shared__ unsigned short lds[];
  unsigned short* sA0 = lds;
  unsigned short* sA1 = lds + 16384;
  unsigned short* sB0 = lds + 32768;
  unsigned short* sB1 = lds + 49152;

  const int nbn = N >> 8;
  const int bid = blockIdx.x;
  const int swz = (bid & 7) * ((int)gridDim.x >> 3) + (bid >> 3);  // XCD swizzle (nwg%8==0)
  const int by = swz / nbn, bx = swz % nbn;
  const int tm = by << 8, tn = bx << 8;

  const int tid = threadIdx.x;
  const int wave = tid >> 6, lane = tid & 63;
  const int l31 = lane & 31, hi = lane >> 5;
  const int wm = wave >> 2, wn = wave & 3;
  const int rA = wm * 128 + l31;   // A fragment base row
  const int rB = wn * 64 + l31;    // B fragment base row
  const int r = tid >> 3;
  const int slot = (tid & 7) ^ ((tid >> 3) & 7);

  const unsigned short* Ag = A + (size_t)tm * K_;
  const unsigned short* Bg = Bm + (size_t)tn * K_;
  const size_t hB = (size_t)128 * K_;

  f32x16 acc[4][2];
#pragma unroll
  for (int i = 0; i < 4; ++i)
#pragma unroll
    for (int j = 0; j < 2; ++j)
#pragma unroll
      for (int q = 0; q < 16; ++q) acc[i][j][q] = 0.f;

  bf16x8 bP[4], bQ[4];

  // prologue: t0 full (A0,A1,B0,B1) + t1.B0,B1  (12 loads/thread)
  stage_half(Ag, K_, sA0, r, slot, wave);
  stage_half(Ag + hB, K_, sA0 + 8192, r, slot, wave);
  stage_half(Bg, K_, sB0, r, slot, wave);
  stage_half(Bg + hB, K_, sB0 + 8192, r, slot, wave);
  stage_half(Bg + 64, K_, sB1, r, slot, wave);
  stage_half(Bg + hB + 64, K_, sB1 + 8192, r, slot, wave);
  asm volatile("s_waitcnt vmcnt(4)" ::: "memory");
  __builtin_amdgcn_s_barrier();
  LD_B32(bP, sB0, rB);   // B(t0).nh0 ; drained by ph1's lgkmcnt(0)

  const int NI = E >> 7;  // 2 K-tiles per iteration
#pragma unroll 1
  for (int i = 0; i < NI - 1; ++i)
    k_iter<false>(Ag, Bg, K_, 2 * i, sA0, sA1, sB0, sB1, r, slot, wave, hi, rA, rB, bP, bQ, acc);
  k_iter<true>(Ag, Bg, K_, 2 * (NI - 1), sA0, sA1, sB0, sB1, r, slot, wave, hi, rA, rB, bP, bQ, acc);

  // epilogue: 32x32 C/D layout: col = lane&31, row = (reg&3) + 8*(reg>>2) + 4*hi
#pragma unroll
  for (int ni = 0; ni < 2; ++ni) {
    const int col = tn + wn * 64 + ni * 32 + l31;
    const float bv = bias[col];
#pragma unroll
    for (int mi = 0; mi < 4; ++mi) {
      const int rowb = tm + wm * 128 + mi * 32 + 4 * hi;
#pragma unroll
      for (int reg = 0; reg < 16; ++reg) {
        const int row = rowb + (reg & 3) + 8 * (reg >> 2);
        const float v = acc[mi][ni][reg] + bv;
        if (OUT_BF16)
          ((unsigned short*)C)[(size_t)row * N + col] = f2bf(v);
        else
          ((float*)C)[(size_t)row * N + col] = v;
      }
    }
  }
}

// ---------------- per-token head-mixing attention ----------------
__global__ __launch_bounds__(256) void attn_kernel(const unsigned short* mod,
                                                   const unsigned short* xsg,
                                                   unsigned short* att) {
  __shared__ __align__(16) unsigned short xs_lds[4][16][136];
  __shared__ float w_lds[4][16][17];

  const int wave = threadIdx.x >> 6, lane = threadIdx.x & 63;
  const int token = (blockIdx.x << 2) | wave;
  const unsigned short* modp = mod + (size_t)token * E;
  const unsigned short* xsp  = xsg + (size_t)token * E;
  const int g16 = lane & 15, grp = lane >> 4;

  bf16x8 a[4], b[4];
#pragma unroll
  for (int kk = 0; kk < 4; ++kk) {
    a[kk] = *reinterpret_cast<const bf16x8*>(modp + g16 * DH + kk * 32 + grp * 8);
    b[kk] = *reinterpret_cast<const bf16x8*>(xsp  + g16 * DH + kk * 32 + grp * 8);
  }
#pragma unroll
  for (int kk = 0; kk < 4; ++kk)
    *reinterpret_cast<bf16x8*>(&xs_lds[wave][g16][kk * 32 + grp * 8]) = b[kk];

  f32x4 sc = (f32x4){0.f, 0.f, 0.f, 0.f};
#pragma unroll
  for (int kk = 0; kk < 4; ++kk)
    sc = MFMA16(a[kk], b[kk], sc, 0, 0, 0);

  float w4[4];
#pragma unroll
  for (int j = 0; j < 4; ++j) {
    float s = sc[j];
    float m = s;
#pragma unroll
    for (int off = 1; off < 16; off <<= 1) m = fmaxf(m, __shfl_xor(m, off));
    float e = __expf(s - m);
    float t = e;
#pragma unroll
    for (int off = 1; off < 16; off <<= 1) t += __shfl_xor(t, off);
    w4[j] = e / t;
  }
#pragma unroll
  for (int j = 0; j < 4; ++j) w_lds[wave][grp * 4 + j][g16] = w4[j];

  __syncthreads();

  float acc[32];
#pragma unroll
  for (int i = 0; i < 32; ++i) acc[i] = 0.f;
#pragma unroll
  for (int g = 0; g < 16; ++g) {
    const float wg = w_lds[wave][g16][g];
#pragma unroll
    for (int c = 0; c < 4; ++c) {
      bf16x8 xv = *reinterpret_cast<const bf16x8*>(&xs_lds[wave][g][grp * 32 + c * 8]);
#pragma unroll
      for (int j = 0; j < 8; ++j) acc[c * 8 + j] += wg * (float)xv[j];
    }
  }

  unsigned short* op = att + (size_t)token * E + g16 * DH + grp * 32;
#pragma unroll
  for (int c = 0; c < 4; ++c) {
    u16x8 o;
#pragma unroll
    for (int j = 0; j < 8; ++j) o[j] = f2bf(acc[c * 8 + j]);
    *reinterpret_cast<u16x8*>(op + c * 8) = o;
  }
}

// ---------------- launch ----------------
extern "C" void kernel_launch(void* const* d_in, const int* in_sizes, int n_in,
                              void* d_out, int out_size, void* d_ws, size_t ws_size,
                              hipStream_t stream) {
  const float* x     = (const float*)d_in[0];
  const float* Wz    = (const float*)d_in[1];
  const float* bz    = (const float*)d_in[2];
  const float* Wx    = (const float*)d_in[3];
  const float* bx    = (const float*)d_in[4];
  const float* phase = (const float*)d_in[5];
  const float* Wo    = (const float*)d_in[6];
  const float* bo    = (const float*)d_in[7];

  char* p = (char*)d_ws;
  unsigned short* x_bf   = (unsigned short*)p; p += (size_t)TOK * E * 2;
  unsigned short* mod_bf = (unsigned short*)p; p += (size_t)TOK * E * 2;
  unsigned short* xs_bf  = (unsigned short*)p; p += (size_t)TOK * E * 2;
  unsigned short* wz_bf  = (unsigned short*)p; p += (size_t)E * E * 2;
  unsigned short* wx_bf  = (unsigned short*)p; p += (size_t)E * E * 2;
  unsigned short* wo_bf  = (unsigned short*)p; p += (size_t)E * E * 2;
  float* bz_s            = (float*)p;          p += (size_t)E * 4;
  unsigned short* att_bf = mod_bf;  // in-place per-token rewrite

  hipFuncSetAttribute((const void*)gemm256<true>,
                      hipFuncAttributeMaxDynamicSharedMemorySize, 131072);
  hipFuncSetAttribute((const void*)gemm256<false>,
                      hipFuncAttributeMaxDynamicSharedMemorySize, 131072);

  cvt_plain<<<2048, 256, 0, stream>>>(x, x_bf, TOK * E / 8);
  cvt_plain<<<1024, 256, 0, stream>>>(Wx, wx_bf, E * E / 8);
  cvt_plain<<<1024, 256, 0, stream>>>(Wo, wo_bf, E * E / 8);
  cvt_scaled<<<1024, 256, 0, stream>>>(Wz, phase, wz_bf, E * E / 8);
  scale_bias<<<E / 256, 256, 0, stream>>>(bz, phase, bz_s);

  const dim3 ggrid((TOK / 256) * (E / 256));  // 512 wgs
  gemm256<true><<<ggrid, 512, 131072, stream>>>(x_bf, wz_bf, bz_s, mod_bf, TOK, E, E);
  gemm256<true><<<ggrid, 512, 131072, stream>>>(x_bf, wx_bf, bx, xs_bf, TOK, E, E);
  attn_kernel<<<TOK / 4, 256, 0, stream>>>(mod_bf, xs_bf, att_bf);
  gemm256<false><<<ggrid, 512, 131072, stream>>>(att_bf, wo_bf, bo, (float*)d_out, TOK, E, E);
}

// Round 5
// 465.308 us; speedup vs baseline: 1.1075x; 1.1075x over previous
//
#include <hip/hip_runtime.h>
#include <hip/hip_bf16.h>

#define TOK 16384   // B*S
#define E 2048
#define DH 128

using bf16x8 = __attribute__((ext_vector_type(8))) __bf16;
using f32x4  = __attribute__((ext_vector_type(4))) float;
using u16x8  = __attribute__((ext_vector_type(8))) unsigned short;

static __device__ __forceinline__ unsigned short f2bf(float f) {
  union { float f; unsigned u; } x; x.f = f;
  unsigned r = x.u + 0x7fffu + ((x.u >> 16) & 1u);   // RNE
  return (unsigned short)(r >> 16);
}

static __device__ __forceinline__ void gload_lds16(const unsigned short* g, unsigned short* l) {
  __builtin_amdgcn_global_load_lds(
      (const __attribute__((address_space(1))) void*)g,
      (__attribute__((address_space(3))) void*)l, 16, 0, 0);
}

// ---------------- prep kernels ----------------
__global__ __launch_bounds__(256) void cvt_plain(const float* __restrict__ in,
                                                 unsigned short* __restrict__ out, int n8) {
  int stride = gridDim.x * blockDim.x;
  for (int i = blockIdx.x * blockDim.x + threadIdx.x; i < n8; i += stride) {
    const float4* p = reinterpret_cast<const float4*>(in) + (size_t)i * 2;
    float4 v0 = p[0], v1 = p[1];
    u16x8 o;
    o[0] = f2bf(v0.x); o[1] = f2bf(v0.y); o[2] = f2bf(v0.z); o[3] = f2bf(v0.w);
    o[4] = f2bf(v1.x); o[5] = f2bf(v1.y); o[6] = f2bf(v1.z); o[7] = f2bf(v1.w);
    *(reinterpret_cast<u16x8*>(out) + i) = o;
  }
}

__global__ __launch_bounds__(256) void cvt_scaled(const float* __restrict__ in,
                                                  const float* __restrict__ phase,
                                                  unsigned short* __restrict__ out, int n8) {
  const float rs = 0.08838834764831845f;  // 1/sqrt(128)
  int stride = gridDim.x * blockDim.x;
  for (int i = blockIdx.x * blockDim.x + threadIdx.x; i < n8; i += stride) {
    int row = i >> 8;
    float sc = sinf(phase[row]) * rs;
    const float4* p = reinterpret_cast<const float4*>(in) + (size_t)i * 2;
    float4 v0 = p[0], v1 = p[1];
    u16x8 o;
    o[0] = f2bf(v0.x * sc); o[1] = f2bf(v0.y * sc); o[2] = f2bf(v0.z * sc); o[3] = f2bf(v0.w * sc);
    o[4] = f2bf(v1.x * sc); o[5] = f2bf(v1.y * sc); o[6] = f2bf(v1.z * sc); o[7] = f2bf(v1.w * sc);
    *(reinterpret_cast<u16x8*>(out) + i) = o;
  }
}

__global__ __launch_bounds__(256) void scale_bias(const float* __restrict__ bz,
                                                  const float* __restrict__ phase,
                                                  float* __restrict__ out) {
  const float rs = 0.08838834764831845f;
  int i = blockIdx.x * blockDim.x + threadIdx.x;
  if (i < E) out[i] = bz[i] * sinf(phase[i]) * rs;
}

// ---------------- 256x256 8-phase GEMM, single-barrier phases ----------------
#define MFMA16 __builtin_amdgcn_mfma_f32_16x16x32_bf16

// swizzled LDS fragment read: slot ^= row&7  (slot = 16B unit, 8 per 128B row)
static __device__ __forceinline__ bf16x8 ldf(const unsigned short* buf, int row, int slot) {
  return *reinterpret_cast<const bf16x8*>(buf + row * 64 + ((slot ^ (row & 7)) << 3));
}

// stage one 128-row half-tile: 2 x global_load_lds(16B) per thread.
static __device__ __forceinline__ void stage_half(const unsigned short* gbase, int K_,
                                                  unsigned short* dsthalf,
                                                  int r, int slot, int wave) {
#pragma unroll
  for (int c = 0; c < 2; ++c)
    gload_lds16(gbase + (size_t)(c * 64 + r) * K_ + slot * 8,
                dsthalf + c * 4096 + wave * 512);
}

static __device__ __forceinline__ void quad(f32x4 (&acc)[8][4], const bf16x8 (&a)[4][2],
                                            const bf16x8 (&b)[2][2], int mh, int nh) {
#pragma unroll
  for (int mi = 0; mi < 4; ++mi)
#pragma unroll
    for (int ni = 0; ni < 2; ++ni)
#pragma unroll
      for (int kk = 0; kk < 2; ++kk)
        acc[mh * 4 + mi][nh * 2 + ni] =
            MFMA16(a[mi][kk], b[ni][kk], acc[mh * 4 + mi][nh * 2 + ni], 0, 0, 0);
}

#define PH_BAR()  __builtin_amdgcn_s_barrier()
#define PH_LGKM() asm volatile("s_waitcnt lgkmcnt(0)" ::: "memory")
#define VMCNT(n)  asm volatile("s_waitcnt vmcnt(" #n ")" ::: "memory")
#define PRIO1()   __builtin_amdgcn_s_setprio(1)
#define PRIO0()   __builtin_amdgcn_s_setprio(0)

#define LD_A(dst, buf, base)                                             \
  _Pragma("unroll")                                                      \
  for (int mi = 0; mi < 4; ++mi)                                         \
    _Pragma("unroll")                                                    \
    for (int kk = 0; kk < 2; ++kk)                                       \
      dst[mi][kk] = ldf(buf, (base) + mi * 16, kk * 4 + grp);

#define LD_B(dst, buf, base)                                             \
  _Pragma("unroll")                                                      \
  for (int ni = 0; ni < 2; ++ni)                                         \
    _Pragma("unroll")                                                    \
    for (int kk = 0; kk < 2; ++kk)                                       \
      dst[ni][kk] = ldf(buf, (base) + ni * 16, kk * 4 + grp);

// Phase layout: [reads; (vmcnt pre-BAR where needed); BAR; stage; lgkm; MFMA]
// Single barrier/phase: passing BAR(p) implies every wave executed lgkm(p-1),
// so stage(p) never overwrites a region with undrained reads (regions of
// stage(p) and reads(p) verified disjoint for all 8 phases).
template <bool LAST>
static __device__ __forceinline__ void k_iter(
    const unsigned short* __restrict__ Ag, const unsigned short* __restrict__ Bg,
    int K_, int t,
    unsigned short* sA0, unsigned short* sA1, unsigned short* sB0, unsigned short* sB1,
    int r, int slot, int wave, int grp, int rA, int rB,
    bf16x8 (&bP)[2][2], bf16x8 (&bQ)[2][2], f32x4 (&acc)[8][4]) {
  const size_t k1 = (size_t)(t + 1) * 64, k2 = (size_t)(t + 2) * 64, k3 = (size_t)(t + 3) * 64;
  const size_t hB = (size_t)128 * K_;
  bf16x8 aF[4][2], b1F[2][2];

  // ---- ph1: reads A.mh0 ; stage t+1.A0 -> sA1.h0 ; MFMA (0,0) w/ bP
  LD_A(aF, sA0, rA);
  PH_BAR();
  stage_half(Ag + k1, K_, sA1, r, slot, wave);
  PH_LGKM();
  PRIO1(); quad(acc, aF, bP, 0, 0); PRIO0();

  // ---- ph2: reads B.nh1 ; stage t+1.A1 -> sA1.h1 ; MFMA (0,1)
  LD_B(b1F, sB0, rB + 32);
  PH_BAR();
  stage_half(Ag + hB + k1, K_, sA1 + 8192, r, slot, wave);
  PH_LGKM();
  PRIO1(); quad(acc, aF, b1F, 0, 1); PRIO0();

  // ---- ph3: reads A.mh1 ; vmcnt(4) proves B(t+1) before BAR ; stage t+2.B0
  LD_A(aF, sA0, rA + 64);
  VMCNT(4);
  PH_BAR();
  if (!LAST) stage_half(Bg + k2, K_, sB0, r, slot, wave);
  PH_LGKM();
  PRIO1(); quad(acc, aF, b1F, 1, 1); PRIO0();

  // ---- ph4: reads bQ = B(t+1).nh0 (safe: ph3 vmcnt+BAR) ; vmcnt proves A(t+1) ; stage t+2.B1
  LD_B(bQ, sB1, rB);
  if (!LAST) { VMCNT(2); } else { VMCNT(0); }
  PH_BAR();
  if (!LAST) stage_half(Bg + hB + k2, K_, sB0 + 8192, r, slot, wave);
  PH_LGKM();
  PRIO1(); quad(acc, aF, bP, 1, 0); PRIO0();

  // ---- ph5: reads A(t+1).mh0 ; stage t+2.A0 -> sA0.h0 ; MFMA (0,0) w/ bQ
  LD_A(aF, sA1, rA);
  PH_BAR();
  if (!LAST) stage_half(Ag + k2, K_, sA0, r, slot, wave);
  PH_LGKM();
  PRIO1(); quad(acc, aF, bQ, 0, 0); PRIO0();

  // ---- ph6: reads B(t+1).nh1 ; stage t+2.A1
  LD_B(b1F, sB1, rB + 32);
  PH_BAR();
  if (!LAST) stage_half(Ag + hB + k2, K_, sA0 + 8192, r, slot, wave);
  PH_LGKM();
  PRIO1(); quad(acc, aF, b1F, 0, 1); PRIO0();

  // ---- ph7: reads A(t+1).mh1 ; vmcnt(4) proves B(t+2) ; stage t+3.B0
  LD_A(aF, sA1, rA + 64);
  if (!LAST) { VMCNT(4); }
  PH_BAR();
  if (!LAST) stage_half(Bg + k3, K_, sB1, r, slot, wave);
  PH_LGKM();
  PRIO1(); quad(acc, aF, b1F, 1, 1); PRIO0();

  // ---- ph8: reads bP = B(t+2).nh0 ; vmcnt(2) proves A(t+2) ; stage t+3.B1
  if (!LAST) {
    LD_B(bP, sB0, rB);
    VMCNT(2);
  }
  PH_BAR();
  if (!LAST) stage_half(Bg + hB + k3, K_, sB1 + 8192, r, slot, wave);
  PH_LGKM();
  PRIO1(); quad(acc, aF, bQ, 1, 0); PRIO0();
}

template <bool OUT_BF16>
__global__ __launch_bounds__(512, 2) void gemm256(const unsigned short* __restrict__ A,
                                                  const unsigned short* __restrict__ Bm,
                                                  const float* __restrict__ bias,
                                                  void* __restrict__ C,
                                                  int M, int N, int K_) {
  extern __shared__ unsigned short lds[];
  unsigned short* sA0 = lds;
  unsigned short* sA1 = lds + 16384;
  unsigned short* sB0 = lds + 32768;
  unsigned short* sB1 = lds + 49152;

  const int nbn = N >> 8;
  const int bid = blockIdx.x;
  const int swz = (bid & 7) * ((int)gridDim.x >> 3) + (bid >> 3);  // XCD swizzle (nwg%8==0)
  const int by = swz / nbn, bx = swz % nbn;
  const int tm = by << 8, tn = bx << 8;

  const int tid = threadIdx.x;
  const int wave = tid >> 6, lane = tid & 63;
  const int g16 = lane & 15, grp = lane >> 4;
  const int wm = wave >> 2, wn = wave & 3;
  const int rA = wm * 128 + g16;
  const int rB = wn * 64 + g16;
  const int r = tid >> 3;
  const int slot = (tid & 7) ^ ((tid >> 3) & 7);

  const unsigned short* Ag = A + (size_t)tm * K_;
  const unsigned short* Bg = Bm + (size_t)tn * K_;
  const size_t hB = (size_t)128 * K_;

  f32x4 acc[8][4];
#pragma unroll
  for (int i = 0; i < 8; ++i)
#pragma unroll
    for (int j = 0; j < 4; ++j) acc[i][j] = (f32x4){0.f, 0.f, 0.f, 0.f};

  bf16x8 bP[2][2], bQ[2][2];

  // prologue: t0 full (A0,A1,B0,B1) + t1.B0,B1  (12 loads/thread)
  stage_half(Ag, K_, sA0, r, slot, wave);
  stage_half(Ag + hB, K_, sA0 + 8192, r, slot, wave);
  stage_half(Bg, K_, sB0, r, slot, wave);
  stage_half(Bg + hB, K_, sB0 + 8192, r, slot, wave);
  stage_half(Bg + 64, K_, sB1, r, slot, wave);
  stage_half(Bg + hB + 64, K_, sB1 + 8192, r, slot, wave);
  VMCNT(4);                      // drain A(0),B(0); leave B(1) in flight
  __builtin_amdgcn_s_barrier();  // all waves drained their own -> tiles landed
  LD_B(bP, sB0, rB);             // B(t0).nh0 ; drained by ph1's lgkmcnt(0)

  const int NI = E >> 7;  // 2 K-tiles per iteration
#pragma unroll 1
  for (int i = 0; i < NI - 1; ++i)
    k_iter<false>(Ag, Bg, K_, 2 * i, sA0, sA1, sB0, sB1, r, slot, wave, grp, rA, rB, bP, bQ, acc);
  k_iter<true>(Ag, Bg, K_, 2 * (NI - 1), sA0, sA1, sB0, sB1, r, slot, wave, grp, rA, rB, bP, bQ, acc);

  // epilogue: 16x16 C/D layout: row = (lane>>4)*4 + j, col = lane&15
#pragma unroll
  for (int mi = 0; mi < 8; ++mi) {
#pragma unroll
    for (int ni = 0; ni < 4; ++ni) {
      const int row = tm + wm * 128 + mi * 16 + grp * 4;
      const int col = tn + wn * 64 + ni * 16 + g16;
      const float bv = bias[col];
#pragma unroll
      for (int j = 0; j < 4; ++j) {
        const float v = acc[mi][ni][j] + bv;
        if (OUT_BF16)
          ((unsigned short*)C)[(size_t)(row + j) * N + col] = f2bf(v);
        else
          ((float*)C)[(size_t)(row + j) * N + col] = v;
      }
    }
  }
}

// ---------------- per-token head-mixing attention ----------------
__global__ __launch_bounds__(256) void attn_kernel(const unsigned short* mod,
                                                   const unsigned short* xsg,
                                                   unsigned short* att) {
  __shared__ __align__(16) unsigned short xs_lds[4][16][136];
  __shared__ float w_lds[4][16][17];

  const int wave = threadIdx.x >> 6, lane = threadIdx.x & 63;
  const int token = (blockIdx.x << 2) | wave;
  const unsigned short* modp = mod + (size_t)token * E;
  const unsigned short* xsp  = xsg + (size_t)token * E;
  const int g16 = lane & 15, grp = lane >> 4;

  bf16x8 a[4], b[4];
#pragma unroll
  for (int kk = 0; kk < 4; ++kk) {
    a[kk] = *reinterpret_cast<const bf16x8*>(modp + g16 * DH + kk * 32 + grp * 8);
    b[kk] = *reinterpret_cast<const bf16x8*>(xsp  + g16 * DH + kk * 32 + grp * 8);
  }
#pragma unroll
  for (int kk = 0; kk < 4; ++kk)
    *reinterpret_cast<bf16x8*>(&xs_lds[wave][g16][kk * 32 + grp * 8]) = b[kk];

  f32x4 sc = (f32x4){0.f, 0.f, 0.f, 0.f};
#pragma unroll
  for (int kk = 0; kk < 4; ++kk)
    sc = MFMA16(a[kk], b[kk], sc, 0, 0, 0);

  float w4[4];
#pragma unroll
  for (int j = 0; j < 4; ++j) {
    float s = sc[j];
    float m = s;
#pragma unroll
    for (int off = 1; off < 16; off <<= 1) m = fmaxf(m, __shfl_xor(m, off));
    float e = __expf(s - m);
    float t = e;
#pragma unroll
    for (int off = 1; off < 16; off <<= 1) t += __shfl_xor(t, off);
    w4[j] = e / t;
  }
#pragma unroll
  for (int j = 0; j < 4; ++j) w_lds[wave][grp * 4 + j][g16] = w4[j];

  __syncthreads();

  float acc[32];
#pragma unroll
  for (int i = 0; i < 32; ++i) acc[i] = 0.f;
#pragma unroll
  for (int g = 0; g < 16; ++g) {
    const float wg = w_lds[wave][g16][g];
#pragma unroll
    for (int c = 0; c < 4; ++c) {
      bf16x8 xv = *reinterpret_cast<const bf16x8*>(&xs_lds[wave][g][grp * 32 + c * 8]);
#pragma unroll
      for (int j = 0; j < 8; ++j) acc[c * 8 + j] += wg * (float)xv[j];
    }
  }

  unsigned short* op = att + (size_t)token * E + g16 * DH + grp * 32;
#pragma unroll
  for (int c = 0; c < 4; ++c) {
    u16x8 o;
#pragma unroll
    for (int j = 0; j < 8; ++j) o[j] = f2bf(acc[c * 8 + j]);
    *reinterpret_cast<u16x8*>(op + c * 8) = o;
  }
}

// ---------------- launch ----------------
extern "C" void kernel_launch(void* const* d_in, const int* in_sizes, int n_in,
                              void* d_out, int out_size, void* d_ws, size_t ws_size,
                              hipStream_t stream) {
  const float* x     = (const float*)d_in[0];
  const float* Wz    = (const float*)d_in[1];
  const float* bz    = (const float*)d_in[2];
  const float* Wx    = (const float*)d_in[3];
  const float* bx    = (const float*)d_in[4];
  const float* phase = (const float*)d_in[5];
  const float* Wo    = (const float*)d_in[6];
  const float* bo    = (const float*)d_in[7];

  char* p = (char*)d_ws;
  unsigned short* x_bf   = (unsigned short*)p; p += (size_t)TOK * E * 2;
  unsigned short* mod_bf = (unsigned short*)p; p += (size_t)TOK * E * 2;
  unsigned short* xs_bf  = (unsigned short*)p; p += (size_t)TOK * E * 2;
  unsigned short* wz_bf  = (unsigned short*)p; p += (size_t)E * E * 2;
  unsigned short* wx_bf  = (unsigned short*)p; p += (size_t)E * E * 2;
  unsigned short* wo_bf  = (unsigned short*)p; p += (size_t)E * E * 2;
  float* bz_s            = (float*)p;          p += (size_t)E * 4;
  unsigned short* att_bf = mod_bf;  // in-place per-token rewrite

  hipFuncSetAttribute((const void*)gemm256<true>,
                      hipFuncAttributeMaxDynamicSharedMemorySize, 131072);
  hipFuncSetAttribute((const void*)gemm256<false>,
                      hipFuncAttributeMaxDynamicSharedMemorySize, 131072);

  cvt_plain<<<2048, 256, 0, stream>>>(x, x_bf, TOK * E / 8);
  cvt_plain<<<1024, 256, 0, stream>>>(Wx, wx_bf, E * E / 8);
  cvt_plain<<<1024, 256, 0, stream>>>(Wo, wo_bf, E * E / 8);
  cvt_scaled<<<1024, 256, 0, stream>>>(Wz, phase, wz_bf, E * E / 8);
  scale_bias<<<E / 256, 256, 0, stream>>>(bz, phase, bz_s);

  const dim3 ggrid((TOK / 256) * (E / 256));  // 512 wgs
  gemm256<true><<<ggrid, 512, 131072, stream>>>(x_bf, wz_bf, bz_s, mod_bf, TOK, E, E);
  gemm256<true><<<ggrid, 512, 131072, stream>>>(x_bf, wx_bf, bx, xs_bf, TOK, E, E);
  attn_kernel<<<TOK / 4, 256, 0, stream>>>(mod_bf, xs_bf, att_bf);
  gemm256<false><<<ggrid, 512, 131072, stream>>>(att_bf, wo_bf, bo, (float*)d_out, TOK, E, E);
}